// Round 1
// baseline (875.543 us; speedup 1.0000x reference)
//
#include <hip/hip_runtime.h>

#define NN 50000
#define EE 800000
#define ET 850000      // EE + NN self loops
#define FIN 256
#define HD 8
#define C1 16
#define HC 128         // HD*C1
#define NC 40
#define NEG 0.2f
#define SCAN_B 512
#define SCAN_NB 98     // ceil(NN/512)

__device__ __forceinline__ float leaky(float v){ return v > 0.f ? v : NEG * v; }

// float atomic max via int/uint trick (no NaNs in this workload)
__device__ __forceinline__ void atomicMaxF(float* a, float v){
  if (v >= 0.f) atomicMax((int*)a, __float_as_int(v));
  else          atomicMin((unsigned int*)a, __float_as_uint(v));
}

// K1: h1[N,128] = x[N,256] @ W1[256,128].  8 rows per block, 128 threads = cols.
__global__ __launch_bounds__(128) void k_gemm1(const float* __restrict__ x,
                                               const float* __restrict__ W1,
                                               float* __restrict__ h1){
  __shared__ float xs[8][FIN];
  const int r0 = blockIdx.x * 8;
  const int tid = threadIdx.x;
  for (int i = tid; i < 8 * FIN; i += 128)
    xs[i / FIN][i % FIN] = x[(size_t)(r0 + i / FIN) * FIN + (i % FIN)];
  __syncthreads();
  float acc[8];
#pragma unroll
  for (int r = 0; r < 8; r++) acc[r] = 0.f;
  for (int k = 0; k < FIN; k++){
    float w = W1[k * HC + tid];
#pragma unroll
    for (int r = 0; r < 8; r++) acc[r] += xs[r][k] * w;
  }
#pragma unroll
  for (int r = 0; r < 8; r++) h1[(size_t)(r0 + r) * HC + tid] = acc[r];
}

// K2: per (n,h) attention sums; init m1 with self-loop logit; counts[n] = 1 (self loop)
__global__ void k_att1(const float* __restrict__ h1,
                       const float* __restrict__ att_s, const float* __restrict__ att_d,
                       float* __restrict__ as1, float* __restrict__ ad1,
                       float* __restrict__ m1, int* __restrict__ counts){
  int idx = blockIdx.x * blockDim.x + threadIdx.x;
  if (idx >= NN * HD) return;
  int n = idx >> 3, h = idx & 7;
  const float* hp = h1 + (size_t)n * HC + h * C1;
  float s = 0.f, d = 0.f;
#pragma unroll
  for (int c = 0; c < C1; c++){
    float v = hp[c];
    s += v * att_s[h * C1 + c];
    d += v * att_d[h * C1 + c];
  }
  as1[idx] = s; ad1[idx] = d;
  m1[idx] = leaky(s + d);          // self-loop logit seeds the segment max
  if (h == 0) counts[n] = 1;       // self loop contributes 1 to in-degree
}

// K3: real edges -> segment max (all 8 heads) + in-degree histogram
__global__ void k_max1(const int* __restrict__ ei,
                       const float* __restrict__ as1, const float* __restrict__ ad1,
                       float* __restrict__ m1, int* __restrict__ counts){
  int e = blockIdx.x * blockDim.x + threadIdx.x;
  if (e >= EE) return;
  int s = ei[e], d = ei[EE + e];
  atomicAdd(&counts[d], 1);
#pragma unroll
  for (int h = 0; h < HD; h++)
    atomicMaxF(&m1[d * 8 + h], leaky(as1[s * 8 + h] + ad1[d * 8 + h]));
}

// K5a/b/c: exclusive scan of counts -> offs[0..NN], plus cursor copy
__global__ __launch_bounds__(SCAN_B) void k_scan1(const int* __restrict__ counts,
                                                  int* __restrict__ offs,
                                                  int* __restrict__ bsums){
  __shared__ int sm[SCAN_B];
  int b = blockIdx.x, t = threadIdx.x, i = b * SCAN_B + t;
  int v = (i < NN) ? counts[i] : 0;
  sm[t] = v; __syncthreads();
  for (int d = 1; d < SCAN_B; d <<= 1){
    int u = (t >= d) ? sm[t - d] : 0;
    __syncthreads();
    sm[t] += u;
    __syncthreads();
  }
  if (i < NN) offs[i + 1] = sm[t];      // block-local inclusive
  if (t == SCAN_B - 1) bsums[b] = sm[t];
}

__global__ void k_scan2(int* __restrict__ bsums){
  if (blockIdx.x == 0 && threadIdx.x == 0){
    int run = 0;
    for (int b = 0; b < SCAN_NB; b++){ int v = bsums[b]; bsums[b] = run; run += v; }
  }
}

__global__ __launch_bounds__(SCAN_B) void k_scan3(int* __restrict__ offs,
                                                  const int* __restrict__ bsums,
                                                  int* __restrict__ cursor){
  int b = blockIdx.x, t = threadIdx.x, i = b * SCAN_B + t;
  if (i < NN){
    int v = offs[i + 1] + bsums[b];
    offs[i + 1] = v;
    if (i + 1 < NN) cursor[i + 1] = v;
  }
  if (b == 0 && t == 0){ offs[0] = 0; cursor[0] = 0; }
}

// K6: scatter edge ids into CSR order by dst (self loops encoded as e = EE + n)
__global__ void k_scatter(const int* __restrict__ ei, int* __restrict__ cursor,
                          int* __restrict__ perm){
  int e = blockIdx.x * blockDim.x + threadIdx.x;
  if (e >= ET) return;
  int d = (e < EE) ? ei[EE + e] : (e - EE);
  int pos = atomicAdd(&cursor[d], 1);
  perm[pos] = e;
}

// K7: layer-1 softmax-aggregate. One block (128 thr) per node; thread = (head, chan).
__global__ __launch_bounds__(128) void k_agg1(const int* __restrict__ ei,
                                              const int* __restrict__ offs,
                                              const int* __restrict__ perm,
                                              const float* __restrict__ as1,
                                              const float* __restrict__ ad1,
                                              const float* __restrict__ m1,
                                              const float* __restrict__ h1,
                                              const float* __restrict__ b1,
                                              float* __restrict__ h2){
  const int n = blockIdx.x, tid = threadIdx.x;
  const int off = offs[n], deg = offs[n + 1] - off;
  const int h = tid >> 4, k = tid & 15;
  __shared__ float den_s[HD];
  const float mg  = m1[n * 8 + h];
  const float adg = ad1[n * 8 + h];
  // denominator: 16 lanes per head stride the edge list
  float part = 0.f;
  for (int i = k; i < deg; i += 16){
    int e = perm[off + i];
    int s = (e < EE) ? ei[e] : (e - EE);
    part += __expf(leaky(as1[s * 8 + h] + adg) - mg);
  }
#pragma unroll
  for (int o = 8; o; o >>= 1) part += __shfl_down(part, o, 16);
  if (k == 0) den_s[h] = part;
  __syncthreads();
  const float dd = den_s[h] + 1e-16f;
  float acc = 0.f;
  for (int i = 0; i < deg; i++){
    int e = perm[off + i];
    int s = (e < EE) ? ei[e] : (e - EE);
    float w = __expf(leaky(as1[s * 8 + h] + adg) - mg) / dd;
    acc += w * h1[(size_t)s * HC + tid];
  }
  float v = acc + b1[tid];
  h2[(size_t)n * HC + tid] = (v > 0.f) ? v : (__expf(v) - 1.f);   // ELU
}

// K8: g[N,40] = h2 @ W2; att2 sums; m2 seeded with self-loop logit
__global__ __launch_bounds__(64) void k_gemm2(const float* __restrict__ h2,
                                              const float* __restrict__ W2,
                                              const float* __restrict__ att_s2,
                                              const float* __restrict__ att_d2,
                                              float* __restrict__ g,
                                              float* __restrict__ as2,
                                              float* __restrict__ ad2,
                                              float* __restrict__ m2){
  const int n = blockIdx.x, tid = threadIdx.x;
  __shared__ float hs[HC];
  __shared__ float gs[NC];
  for (int i = tid; i < HC; i += 64) hs[i] = h2[(size_t)n * HC + i];
  __syncthreads();
  if (tid < NC){
    float a = 0.f;
    for (int kk = 0; kk < HC; kk++) a += hs[kk] * W2[kk * NC + tid];
    gs[tid] = a;
    g[(size_t)n * NC + tid] = a;
  }
  __syncthreads();
  if (tid == 0){
    float s = 0.f, d = 0.f;
    for (int j = 0; j < NC; j++){ s += gs[j] * att_s2[j]; d += gs[j] * att_d2[j]; }
    as2[n] = s; ad2[n] = d; m2[n] = leaky(s + d);
  }
}

// K9: layer-2 segment max over real edges
__global__ void k_max2(const int* __restrict__ ei, const float* __restrict__ as2,
                       const float* __restrict__ ad2, float* __restrict__ m2){
  int e = blockIdx.x * blockDim.x + threadIdx.x;
  if (e >= EE) return;
  int s = ei[e], d = ei[EE + e];
  atomicMaxF(&m2[d], leaky(as2[s] + ad2[d]));
}

// K10: layer-2 softmax-aggregate + bias + log_softmax. One wave per node.
__global__ __launch_bounds__(64) void k_agg2(const int* __restrict__ ei,
                                             const int* __restrict__ offs,
                                             const int* __restrict__ perm,
                                             const float* __restrict__ as2,
                                             const float* __restrict__ ad2,
                                             const float* __restrict__ m2,
                                             const float* __restrict__ g,
                                             const float* __restrict__ b2,
                                             float* __restrict__ out){
  const int n = blockIdx.x, tid = threadIdx.x;
  const int off = offs[n], deg = offs[n + 1] - off;
  const float m = m2[n], ad = ad2[n];
  float part = 0.f;
  for (int i = tid; i < deg; i += 64){
    int e = perm[off + i];
    int s = (e < EE) ? ei[e] : (e - EE);
    part += __expf(leaky(as2[s] + ad) - m);
  }
#pragma unroll
  for (int o = 32; o; o >>= 1) part += __shfl_down(part, o, 64);
  const float den = __shfl(part, 0, 64) + 1e-16f;
  __shared__ float fin[NC];
  if (tid < NC){
    float acc = 0.f;
    for (int i = 0; i < deg; i++){
      int e = perm[off + i];
      int s = (e < EE) ? ei[e] : (e - EE);
      float w = __expf(leaky(as2[s] + ad) - m) / den;
      acc += w * g[(size_t)s * NC + tid];
    }
    float f = acc + b2[tid];
    out[(size_t)n * NC + tid] = f;
    fin[tid] = f;
  }
  __syncthreads();
  float v = (tid < NC) ? fin[tid] : -3.4e38f;
  float mx = v;
#pragma unroll
  for (int o = 32; o; o >>= 1) mx = fmaxf(mx, __shfl_down(mx, o, 64));
  mx = __shfl(mx, 0, 64);
  float ex = (tid < NC) ? __expf(v - mx) : 0.f;
#pragma unroll
  for (int o = 32; o; o >>= 1) ex += __shfl_down(ex, o, 64);
  float lse = mx + __logf(__shfl(ex, 0, 64));
  if (tid < NC) out[(size_t)(NN * NC) + (size_t)n * NC + tid] = fin[tid] - lse;
}

extern "C" void kernel_launch(void* const* d_in, const int* in_sizes, int n_in,
                              void* d_out, int out_size, void* d_ws, size_t ws_size,
                              hipStream_t stream){
  const float* x      = (const float*)d_in[0];
  const int*   ei     = (const int*)  d_in[1];   // [2,E] flat int32
  const float* W1     = (const float*)d_in[3];
  const float* att_s1 = (const float*)d_in[4];
  const float* att_d1 = (const float*)d_in[5];
  const float* b1     = (const float*)d_in[6];
  const float* W2     = (const float*)d_in[7];
  const float* att_s2 = (const float*)d_in[8];
  const float* att_d2 = (const float*)d_in[9];
  const float* b2     = (const float*)d_in[10];
  float* out = (float*)d_out;

  float* p   = (float*)d_ws;
  float* h1  = p; p += (size_t)NN * HC;
  float* h2  = p; p += (size_t)NN * HC;
  float* as1 = p; p += NN * HD;
  float* ad1 = p; p += NN * HD;
  float* m1  = p; p += NN * HD;
  float* g   = p; p += NN * NC;
  float* as2 = p; p += NN;
  float* ad2 = p; p += NN;
  float* m2  = p; p += NN;
  int* counts = (int*)p;
  int* offs   = counts + NN;          // NN+1
  int* cursor = offs + NN + 4;        // padded
  int* perm   = cursor + NN;          // ET
  int* bsums  = perm + ET;            // SCAN_NB

  k_gemm1  <<<NN / 8, 128, 0, stream>>>(x, W1, h1);
  k_att1   <<<(NN * HD + 255) / 256, 256, 0, stream>>>(h1, att_s1, att_d1, as1, ad1, m1, counts);
  k_max1   <<<(EE + 255) / 256, 256, 0, stream>>>(ei, as1, ad1, m1, counts);
  k_scan1  <<<SCAN_NB, SCAN_B, 0, stream>>>(counts, offs, bsums);
  k_scan2  <<<1, 64, 0, stream>>>(bsums);
  k_scan3  <<<SCAN_NB, SCAN_B, 0, stream>>>(offs, bsums, cursor);
  k_scatter<<<(ET + 255) / 256, 256, 0, stream>>>(ei, cursor, perm);
  k_agg1   <<<NN, 128, 0, stream>>>(ei, offs, perm, as1, ad1, m1, h1, b1, h2);
  k_gemm2  <<<NN, 64, 0, stream>>>(h2, W2, att_s2, att_d2, g, as2, ad2, m2);
  k_max2   <<<(EE + 255) / 256, 256, 0, stream>>>(ei, as2, ad2, m2);
  k_agg2   <<<NN, 64, 0, stream>>>(ei, offs, perm, as2, ad2, m2, g, b2, out);
}

// Round 2
// 590.815 us; speedup vs baseline: 1.4819x; 1.4819x over previous
//
#include <hip/hip_runtime.h>

#define NN 50000
#define EE 800000
#define ET 850000      // EE + NN self loops
#define FIN 256
#define HD 8
#define C1 16
#define HC 128         // HD*C1
#define NC 40
#define NEG 0.2f
#define SCAN_B 512
#define SCAN_NB 98     // ceil(NN/512)

__device__ __forceinline__ float leaky(float v){ return v > 0.f ? v : NEG * v; }

// K1: h1[N,128] = x[N,256] @ W1[256,128].  8 rows per block, 128 threads = cols.
__global__ __launch_bounds__(128) void k_gemm1(const float* __restrict__ x,
                                               const float* __restrict__ W1,
                                               float* __restrict__ h1){
  __shared__ float xs[8][FIN];
  const int r0 = blockIdx.x * 8;
  const int tid = threadIdx.x;
  for (int i = tid; i < 8 * FIN; i += 128)
    xs[i / FIN][i % FIN] = x[(size_t)(r0 + i / FIN) * FIN + (i % FIN)];
  __syncthreads();
  float acc[8];
#pragma unroll
  for (int r = 0; r < 8; r++) acc[r] = 0.f;
  for (int k = 0; k < FIN; k++){
    float w = W1[k * HC + tid];
#pragma unroll
    for (int r = 0; r < 8; r++) acc[r] += xs[r][k] * w;
  }
#pragma unroll
  for (int r = 0; r < 8; r++) h1[(size_t)(r0 + r) * HC + tid] = acc[r];
}

// K2: per (n,h) attention sums; counts[n] = 1 (self loop)
__global__ void k_att1(const float* __restrict__ h1,
                       const float* __restrict__ att_s, const float* __restrict__ att_d,
                       float* __restrict__ as1, float* __restrict__ ad1,
                       int* __restrict__ counts){
  int idx = blockIdx.x * blockDim.x + threadIdx.x;
  if (idx >= NN * HD) return;
  int n = idx >> 3, h = idx & 7;
  const float* hp = h1 + (size_t)n * HC + h * C1;
  float s = 0.f, d = 0.f;
#pragma unroll
  for (int c = 0; c < C1; c++){
    float v = hp[c];
    s += v * att_s[h * C1 + c];
    d += v * att_d[h * C1 + c];
  }
  as1[idx] = s; ad1[idx] = d;
  if (h == 0) counts[n] = 1;       // self loop contributes 1 to in-degree
}

// K3: in-degree histogram (one atomic per edge)
__global__ void k_hist(const int* __restrict__ ei, int* __restrict__ counts){
  int e = blockIdx.x * blockDim.x + threadIdx.x;
  if (e >= EE) return;
  atomicAdd(&counts[ei[EE + e]], 1);
}

// K5a/b/c: exclusive scan of counts -> offs[0..NN], plus cursor copy
__global__ __launch_bounds__(SCAN_B) void k_scan1(const int* __restrict__ counts,
                                                  int* __restrict__ offs,
                                                  int* __restrict__ bsums){
  __shared__ int sm[SCAN_B];
  int b = blockIdx.x, t = threadIdx.x, i = b * SCAN_B + t;
  int v = (i < NN) ? counts[i] : 0;
  sm[t] = v; __syncthreads();
  for (int d = 1; d < SCAN_B; d <<= 1){
    int u = (t >= d) ? sm[t - d] : 0;
    __syncthreads();
    sm[t] += u;
    __syncthreads();
  }
  if (i < NN) offs[i + 1] = sm[t];      // block-local inclusive
  if (t == SCAN_B - 1) bsums[b] = sm[t];
}

__global__ void k_scan2(int* __restrict__ bsums){
  if (blockIdx.x == 0 && threadIdx.x == 0){
    int run = 0;
    for (int b = 0; b < SCAN_NB; b++){ int v = bsums[b]; bsums[b] = run; run += v; }
  }
}

__global__ __launch_bounds__(SCAN_B) void k_scan3(int* __restrict__ offs,
                                                  const int* __restrict__ bsums,
                                                  int* __restrict__ cursor){
  int b = blockIdx.x, t = threadIdx.x, i = b * SCAN_B + t;
  if (i < NN){
    int v = offs[i + 1] + bsums[b];
    offs[i + 1] = v;
    if (i + 1 < NN) cursor[i + 1] = v;
  }
  if (b == 0 && t == 0){ offs[0] = 0; cursor[0] = 0; }
}

// K6: scatter edge ids into CSR order by dst (self loops encoded as e = EE + n)
__global__ void k_scatter(const int* __restrict__ ei, int* __restrict__ cursor,
                          int* __restrict__ perm){
  int e = blockIdx.x * blockDim.x + threadIdx.x;
  if (e >= ET) return;
  int d = (e < EE) ? ei[EE + e] : (e - EE);
  int pos = atomicAdd(&cursor[d], 1);
  perm[pos] = e;
}

// K7: layer-1 softmax-aggregate with ONLINE max+sum (no global segment-max pass).
// One block (128 thr) per node; thread = (head h = tid>>4, chan k = tid&15).
__global__ __launch_bounds__(128) void k_agg1(const int* __restrict__ ei,
                                              const int* __restrict__ offs,
                                              const int* __restrict__ perm,
                                              const float* __restrict__ as1,
                                              const float* __restrict__ ad1,
                                              const float* __restrict__ h1,
                                              const float* __restrict__ b1,
                                              float* __restrict__ h2){
  const int n = blockIdx.x, tid = threadIdx.x;
  const int off = offs[n], deg = offs[n + 1] - off;
  const int h = tid >> 4, k = tid & 15;
  const float adg = ad1[n * 8 + h];
  // pass 1: online max + rescaled sum; 16 lanes per head stride the edge list
  float ml = -3.0e38f, sl = 0.f;
  for (int i = k; i < deg; i += 16){
    int e = perm[off + i];
    int s = (e < EE) ? ei[e] : (e - EE);
    float v = leaky(as1[s * 8 + h] + adg);
    if (v > ml){ sl = sl * __expf(ml - v) + 1.f; ml = v; }
    else        sl += __expf(v - ml);
  }
  // butterfly combine (max, rescaled sum) across 16 lanes of the head group
#pragma unroll
  for (int o = 1; o < 16; o <<= 1){
    float mo = __shfl_xor(ml, o, 16);
    float so = __shfl_xor(sl, o, 16);
    float mn = fmaxf(ml, mo);
    sl = sl * __expf(ml - mn) + so * __expf(mo - mn);
    ml = mn;
  }
  const float dd = sl + 1e-16f;
  // pass 2: weighted aggregate
  float acc = 0.f;
  for (int i = 0; i < deg; i++){
    int e = perm[off + i];
    int s = (e < EE) ? ei[e] : (e - EE);
    float w = __expf(leaky(as1[s * 8 + h] + adg) - ml) / dd;
    acc += w * h1[(size_t)s * HC + tid];
  }
  float v = acc + b1[tid];
  h2[(size_t)n * HC + tid] = (v > 0.f) ? v : (__expf(v) - 1.f);   // ELU
}

// K8: g[N,40] = h2 @ W2; att2 sums
__global__ __launch_bounds__(64) void k_gemm2(const float* __restrict__ h2,
                                              const float* __restrict__ W2,
                                              const float* __restrict__ att_s2,
                                              const float* __restrict__ att_d2,
                                              float* __restrict__ g,
                                              float* __restrict__ as2,
                                              float* __restrict__ ad2){
  const int n = blockIdx.x, tid = threadIdx.x;
  __shared__ float hs[HC];
  __shared__ float gs[NC];
  for (int i = tid; i < HC; i += 64) hs[i] = h2[(size_t)n * HC + i];
  __syncthreads();
  if (tid < NC){
    float a = 0.f;
    for (int kk = 0; kk < HC; kk++) a += hs[kk] * W2[kk * NC + tid];
    gs[tid] = a;
    g[(size_t)n * NC + tid] = a;
  }
  __syncthreads();
  if (tid == 0){
    float s = 0.f, d = 0.f;
    for (int j = 0; j < NC; j++){ s += gs[j] * att_s2[j]; d += gs[j] * att_d2[j]; }
    as2[n] = s; ad2[n] = d;
  }
}

// K10: layer-2 softmax-aggregate (online max+sum) + bias + log_softmax. One wave per node.
__global__ __launch_bounds__(64) void k_agg2(const int* __restrict__ ei,
                                             const int* __restrict__ offs,
                                             const int* __restrict__ perm,
                                             const float* __restrict__ as2,
                                             const float* __restrict__ ad2,
                                             const float* __restrict__ g,
                                             const float* __restrict__ b2,
                                             float* __restrict__ out){
  const int n = blockIdx.x, tid = threadIdx.x;
  const int off = offs[n], deg = offs[n + 1] - off;
  const float ad = ad2[n];
  float ml = -3.0e38f, sl = 0.f;
  for (int i = tid; i < deg; i += 64){
    int e = perm[off + i];
    int s = (e < EE) ? ei[e] : (e - EE);
    float v = leaky(as2[s] + ad);
    if (v > ml){ sl = sl * __expf(ml - v) + 1.f; ml = v; }
    else        sl += __expf(v - ml);
  }
#pragma unroll
  for (int o = 1; o < 64; o <<= 1){
    float mo = __shfl_xor(ml, o, 64);
    float so = __shfl_xor(sl, o, 64);
    float mn = fmaxf(ml, mo);
    sl = sl * __expf(ml - mn) + so * __expf(mo - mn);
    ml = mn;
  }
  const float den = sl + 1e-16f;
  const float m = ml;
  __shared__ float fin[NC];
  if (tid < NC){
    float acc = 0.f;
    for (int i = 0; i < deg; i++){
      int e = perm[off + i];
      int s = (e < EE) ? ei[e] : (e - EE);
      float w = __expf(leaky(as2[s] + ad) - m) / den;
      acc += w * g[(size_t)s * NC + tid];
    }
    float f = acc + b2[tid];
    out[(size_t)n * NC + tid] = f;
    fin[tid] = f;
  }
  __syncthreads();
  float v = (tid < NC) ? fin[tid] : -3.4e38f;
  float mx = v;
#pragma unroll
  for (int o = 32; o; o >>= 1) mx = fmaxf(mx, __shfl_down(mx, o, 64));
  mx = __shfl(mx, 0, 64);
  float ex = (tid < NC) ? __expf(v - mx) : 0.f;
#pragma unroll
  for (int o = 32; o; o >>= 1) ex += __shfl_down(ex, o, 64);
  float lse = mx + __logf(__shfl(ex, 0, 64));
  if (tid < NC) out[(size_t)(NN * NC) + (size_t)n * NC + tid] = fin[tid] - lse;
}

extern "C" void kernel_launch(void* const* d_in, const int* in_sizes, int n_in,
                              void* d_out, int out_size, void* d_ws, size_t ws_size,
                              hipStream_t stream){
  const float* x      = (const float*)d_in[0];
  const int*   ei     = (const int*)  d_in[1];   // [2,E] flat int32
  const float* W1     = (const float*)d_in[3];
  const float* att_s1 = (const float*)d_in[4];
  const float* att_d1 = (const float*)d_in[5];
  const float* b1     = (const float*)d_in[6];
  const float* W2     = (const float*)d_in[7];
  const float* att_s2 = (const float*)d_in[8];
  const float* att_d2 = (const float*)d_in[9];
  const float* b2     = (const float*)d_in[10];
  float* out = (float*)d_out;

  float* p   = (float*)d_ws;
  float* h1  = p; p += (size_t)NN * HC;
  float* h2  = p; p += (size_t)NN * HC;
  float* as1 = p; p += NN * HD;
  float* ad1 = p; p += NN * HD;
  float* g   = p; p += NN * NC;
  float* as2 = p; p += NN;
  float* ad2 = p; p += NN;
  int* counts = (int*)p;
  int* offs   = counts + NN;          // NN+1
  int* cursor = offs + NN + 4;        // padded
  int* perm   = cursor + NN;          // ET
  int* bsums  = perm + ET;            // SCAN_NB

  k_gemm1  <<<NN / 8, 128, 0, stream>>>(x, W1, h1);
  k_att1   <<<(NN * HD + 255) / 256, 256, 0, stream>>>(h1, att_s1, att_d1, as1, ad1, counts);
  k_hist   <<<(EE + 255) / 256, 256, 0, stream>>>(ei, counts);
  k_scan1  <<<SCAN_NB, SCAN_B, 0, stream>>>(counts, offs, bsums);
  k_scan2  <<<1, 64, 0, stream>>>(bsums);
  k_scan3  <<<SCAN_NB, SCAN_B, 0, stream>>>(offs, bsums, cursor);
  k_scatter<<<(ET + 255) / 256, 256, 0, stream>>>(ei, cursor, perm);
  k_agg1   <<<NN, 128, 0, stream>>>(ei, offs, perm, as1, ad1, h1, b1, h2);
  k_gemm2  <<<NN, 64, 0, stream>>>(h2, W2, att_s2, att_d2, g, as2, ad2);
  k_agg2   <<<NN, 64, 0, stream>>>(ei, offs, perm, as2, ad2, g, b2, out);
}

// Round 3
// 427.843 us; speedup vs baseline: 2.0464x; 1.3809x over previous
//
#include <hip/hip_runtime.h>

#define NN 50000
#define EE 800000
#define ET 850000      // EE + NN self loops
#define FIN 256
#define HD 8
#define C1 16
#define HC 128         // HD*C1
#define NC 40
#define NEG 0.2f
#define SCAN_B 512
#define SCAN_NB 98     // ceil(NN/512)
#define R2 32          // rows per block in k_gemm2

__device__ __forceinline__ float leaky(float v){ return v > 0.f ? v : NEG * v; }

// K1: h1[N,128] = x[N,256] @ W1[256,128], fused attention dots as1/ad1 and counts init.
// 8 rows per block, 128 threads = cols (tid = h*16 + c).
__global__ __launch_bounds__(128) void k_gemm1(const float* __restrict__ x,
                                               const float* __restrict__ W1,
                                               const float* __restrict__ att_s,
                                               const float* __restrict__ att_d,
                                               float* __restrict__ h1,
                                               float* __restrict__ as1,
                                               float* __restrict__ ad1,
                                               int* __restrict__ counts){
  __shared__ float xs[8][FIN];
  const int r0 = blockIdx.x * 8;
  const int tid = threadIdx.x;
  for (int i = tid; i < 8 * FIN; i += 128)
    xs[i / FIN][i % FIN] = x[(size_t)(r0 + i / FIN) * FIN + (i % FIN)];
  __syncthreads();
  float acc[8];
#pragma unroll
  for (int r = 0; r < 8; r++) acc[r] = 0.f;
  for (int k = 0; k < FIN; k++){
    float w = W1[k * HC + tid];
#pragma unroll
    for (int r = 0; r < 8; r++) acc[r] += xs[r][k] * w;
  }
  const float asv = att_s[tid], adv = att_d[tid];
#pragma unroll
  for (int r = 0; r < 8; r++){
    h1[(size_t)(r0 + r) * HC + tid] = acc[r];
    float s = acc[r] * asv, d = acc[r] * adv;
#pragma unroll
    for (int o = 1; o < 16; o <<= 1){ s += __shfl_xor(s, o); d += __shfl_xor(d, o); }
    if ((tid & 15) == 0){
      as1[(r0 + r) * 8 + (tid >> 4)] = s;
      ad1[(r0 + r) * 8 + (tid >> 4)] = d;
    }
  }
  if (tid < 8) counts[r0 + tid] = 1;   // self loop contributes 1 to in-degree
}

// K2: in-degree histogram (one atomic per edge)
__global__ void k_hist(const int* __restrict__ ei, int* __restrict__ counts){
  int e = blockIdx.x * blockDim.x + threadIdx.x;
  if (e >= EE) return;
  atomicAdd(&counts[ei[EE + e]], 1);
}

// K3a/b/c: exclusive scan of counts -> offs[0..NN], plus cursor copy
__global__ __launch_bounds__(SCAN_B) void k_scan1(const int* __restrict__ counts,
                                                  int* __restrict__ offs,
                                                  int* __restrict__ bsums){
  __shared__ int sm[SCAN_B];
  int b = blockIdx.x, t = threadIdx.x, i = b * SCAN_B + t;
  int v = (i < NN) ? counts[i] : 0;
  sm[t] = v; __syncthreads();
  for (int d = 1; d < SCAN_B; d <<= 1){
    int u = (t >= d) ? sm[t - d] : 0;
    __syncthreads();
    sm[t] += u;
    __syncthreads();
  }
  if (i < NN) offs[i + 1] = sm[t];
  if (t == SCAN_B - 1) bsums[b] = sm[t];
}

__global__ void k_scan2(int* __restrict__ bsums){
  if (blockIdx.x == 0 && threadIdx.x == 0){
    int run = 0;
    for (int b = 0; b < SCAN_NB; b++){ int v = bsums[b]; bsums[b] = run; run += v; }
  }
}

__global__ __launch_bounds__(SCAN_B) void k_scan3(int* __restrict__ offs,
                                                  const int* __restrict__ bsums,
                                                  int* __restrict__ cursor){
  int b = blockIdx.x, t = threadIdx.x, i = b * SCAN_B + t;
  if (i < NN){
    int v = offs[i + 1] + bsums[b];
    offs[i + 1] = v;
    if (i + 1 < NN) cursor[i + 1] = v;
  }
  if (b == 0 && t == 0){ offs[0] = 0; cursor[0] = 0; }
}

// K4: scatter SOURCE NODE IDS into CSR-by-dst order (self loops: src = dst = n)
__global__ void k_scatter(const int* __restrict__ ei, int* __restrict__ cursor,
                          int* __restrict__ srcp){
  int e = blockIdx.x * blockDim.x + threadIdx.x;
  if (e >= ET) return;
  int s, d;
  if (e < EE){ s = ei[e]; d = ei[EE + e]; } else { s = d = e - EE; }
  int pos = atomicAdd(&cursor[d], 1);
  srcp[pos] = s;
}

// K5: layer-1 single-pass online-softmax aggregate.
// One wave per node. lane = (half = lane>>5 edge parity, c4 = lane&31 float4 group, head = c4>>2).
__global__ __launch_bounds__(64) void k_agg1(const int* __restrict__ srcp,
                                             const int* __restrict__ offs,
                                             const float* __restrict__ as1,
                                             const float* __restrict__ ad1,
                                             const float* __restrict__ h1,
                                             const float* __restrict__ b1,
                                             float* __restrict__ h2){
  const int n = blockIdx.x, lane = threadIdx.x;
  const int half = lane >> 5, c4 = lane & 31, h = c4 >> 2;
  const int off = offs[n], deg = offs[n + 1] - off;
  const float adg = ad1[n * 8 + h];
  float m = -3.0e38f, den = 0.f;
  float ax = 0.f, ay = 0.f, az = 0.f, aw = 0.f;
  for (int i = half; i < deg; i += 2){
    int s = srcp[off + i];
    const float4 hr = *(const float4*)(h1 + (size_t)s * HC + c4 * 4);
    float v = leaky(as1[s * 8 + h] + adg);
    float mn = fmaxf(m, v);
    float r = __expf(m - mn);
    float w = __expf(v - mn);
    den = den * r + w;
    ax = ax * r + w * hr.x; ay = ay * r + w * hr.y;
    az = az * r + w * hr.z; aw = aw * r + w * hr.w;
    m = mn;
  }
  // combine the two edge-parity halves
  float mo = __shfl_xor(m, 32), dno = __shfl_xor(den, 32);
  float bx = __shfl_xor(ax, 32), by = __shfl_xor(ay, 32);
  float bz = __shfl_xor(az, 32), bw = __shfl_xor(aw, 32);
  float mn = fmaxf(m, mo);
  float ra = __expf(m - mn), rb = __expf(mo - mn);
  den = den * ra + dno * rb;
  ax = ax * ra + bx * rb; ay = ay * ra + by * rb;
  az = az * ra + bz * rb; aw = aw * ra + bw * rb;
  if (half == 0){
    float invd = 1.f / (den + 1e-16f);
    const float4 b4 = ((const float4*)b1)[c4];
    float4 o;
    o.x = ax * invd + b4.x; o.y = ay * invd + b4.y;
    o.z = az * invd + b4.z; o.w = aw * invd + b4.w;
    o.x = (o.x > 0.f) ? o.x : (__expf(o.x) - 1.f);
    o.y = (o.y > 0.f) ? o.y : (__expf(o.y) - 1.f);
    o.z = (o.z > 0.f) ? o.z : (__expf(o.z) - 1.f);
    o.w = (o.w > 0.f) ? o.w : (__expf(o.w) - 1.f);
    *(float4*)(h2 + (size_t)n * HC + c4 * 4) = o;
  }
}

// K6: g[N,40] = h2 @ W2 (32 rows/block, W2+h2 staged in LDS); fused att2 dots.
__global__ __launch_bounds__(256) void k_gemm2(const float* __restrict__ h2,
                                               const float* __restrict__ W2,
                                               const float* __restrict__ att_s2,
                                               const float* __restrict__ att_d2,
                                               float* __restrict__ g,
                                               float* __restrict__ as2,
                                               float* __restrict__ ad2){
  __shared__ float hs[R2][HC + 2];     // pad to 130 to break 8-way row conflicts
  __shared__ float w2s[HC * NC];       // 20 KB
  const int tid = threadIdx.x;
  const int r0 = blockIdx.x * R2;
  for (int i = tid; i < HC * NC; i += 256) w2s[i] = W2[i];
  for (int i = tid; i < R2 * HC; i += 256){
    int r = i >> 7, c = i & 127;
    hs[r][c] = (r0 + r < NN) ? h2[(size_t)(r0 + r) * HC + c] : 0.f;
  }
  __syncthreads();
  const int r = tid >> 3, j = tid & 7;   // 8 threads per row, 5 cols each (stride 8)
  float acc[5] = {0.f, 0.f, 0.f, 0.f, 0.f};
  for (int k = 0; k < HC; k++){
    float hv = hs[r][k];
#pragma unroll
    for (int q = 0; q < 5; q++) acc[q] += hv * w2s[k * NC + j + 8 * q];
  }
  const int node = r0 + r;
  if (node < NN){
    float s = 0.f, d = 0.f;
#pragma unroll
    for (int q = 0; q < 5; q++){
      int c = j + 8 * q;
      g[(size_t)node * NC + c] = acc[q];
      s += acc[q] * att_s2[c];
      d += acc[q] * att_d2[c];
    }
#pragma unroll
    for (int o = 1; o < 8; o <<= 1){ s += __shfl_xor(s, o); d += __shfl_xor(d, o); }
    if (j == 0){ as2[node] = s; ad2[node] = d; }
  }
}

// K7: layer-2 single-pass online-softmax aggregate + bias + log_softmax. One wave/node.
// lane = (half = lane>>5, c2 = lane&31; active channels c2<20 hold float2).
__global__ __launch_bounds__(64) void k_agg2(const int* __restrict__ srcp,
                                             const int* __restrict__ offs,
                                             const float* __restrict__ as2,
                                             const float* __restrict__ ad2,
                                             const float* __restrict__ g,
                                             const float* __restrict__ b2,
                                             float* __restrict__ out){
  const int n = blockIdx.x, lane = threadIdx.x;
  const int half = lane >> 5, c2 = lane & 31;
  const int off = offs[n], deg = offs[n + 1] - off;
  const float ad = ad2[n];
  const bool act = (c2 < 20);
  float m = -3.0e38f, den = 0.f, ax = 0.f, ay = 0.f;
  for (int i = half; i < deg; i += 2){
    int s = srcp[off + i];
    float v = leaky(as2[s] + ad);
    float gx = 0.f, gy = 0.f;
    if (act){
      const float2 gr = *(const float2*)(g + (size_t)s * NC + c2 * 2);
      gx = gr.x; gy = gr.y;
    }
    float mn = fmaxf(m, v);
    float r = __expf(m - mn), w = __expf(v - mn);
    den = den * r + w;
    ax = ax * r + w * gx; ay = ay * r + w * gy;
    m = mn;
  }
  float mo = __shfl_xor(m, 32), dno = __shfl_xor(den, 32);
  float bx = __shfl_xor(ax, 32), by = __shfl_xor(ay, 32);
  float mn = fmaxf(m, mo);
  float ra = __expf(m - mn), rb = __expf(mo - mn);
  den = den * ra + dno * rb;
  ax = ax * ra + bx * rb; ay = ay * ra + by * rb;
  __shared__ float fin[NC];
  if (half == 0 && act){
    float invd = 1.f / (den + 1e-16f);
    float f0 = ax * invd + b2[c2 * 2];
    float f1 = ay * invd + b2[c2 * 2 + 1];
    out[(size_t)n * NC + c2 * 2]     = f0;
    out[(size_t)n * NC + c2 * 2 + 1] = f1;
    fin[c2 * 2] = f0; fin[c2 * 2 + 1] = f1;
  }
  __syncthreads();
  float v = (lane < NC) ? fin[lane] : -3.4e38f;
  float mx = v;
#pragma unroll
  for (int o = 32; o; o >>= 1) mx = fmaxf(mx, __shfl_xor(mx, o));
  float ex = (lane < NC) ? __expf(v - mx) : 0.f;
#pragma unroll
  for (int o = 32; o; o >>= 1) ex += __shfl_xor(ex, o);
  float lse = mx + __logf(ex);
  if (lane < NC) out[(size_t)(NN * NC) + (size_t)n * NC + lane] = v - lse;
}

extern "C" void kernel_launch(void* const* d_in, const int* in_sizes, int n_in,
                              void* d_out, int out_size, void* d_ws, size_t ws_size,
                              hipStream_t stream){
  const float* x      = (const float*)d_in[0];
  const int*   ei     = (const int*)  d_in[1];   // [2,E] flat int32
  const float* W1     = (const float*)d_in[3];
  const float* att_s1 = (const float*)d_in[4];
  const float* att_d1 = (const float*)d_in[5];
  const float* b1     = (const float*)d_in[6];
  const float* W2     = (const float*)d_in[7];
  const float* att_s2 = (const float*)d_in[8];
  const float* att_d2 = (const float*)d_in[9];
  const float* b2     = (const float*)d_in[10];
  float* out = (float*)d_out;

  float* p   = (float*)d_ws;
  float* h1  = p; p += (size_t)NN * HC;
  float* h2  = p; p += (size_t)NN * HC;
  float* as1 = p; p += NN * HD;
  float* ad1 = p; p += NN * HD;
  float* g   = p; p += NN * NC;
  float* as2 = p; p += NN;
  float* ad2 = p; p += NN;
  int* counts = (int*)p;
  int* offs   = counts + NN;          // NN+1
  int* cursor = offs + NN + 4;        // padded
  int* srcp   = cursor + NN;          // ET source-node ids in CSR order
  int* bsums  = srcp + ET;            // SCAN_NB

  k_gemm1  <<<NN / 8, 128, 0, stream>>>(x, W1, att_s1, att_d1, h1, as1, ad1, counts);
  k_hist   <<<(EE + 255) / 256, 256, 0, stream>>>(ei, counts);
  k_scan1  <<<SCAN_NB, SCAN_B, 0, stream>>>(counts, offs, bsums);
  k_scan2  <<<1, 64, 0, stream>>>(bsums);
  k_scan3  <<<SCAN_NB, SCAN_B, 0, stream>>>(offs, bsums, cursor);
  k_scatter<<<(ET + 255) / 256, 256, 0, stream>>>(ei, cursor, srcp);
  k_agg1   <<<NN, 64, 0, stream>>>(srcp, offs, as1, ad1, h1, b1, h2);
  k_gemm2  <<<(NN + R2 - 1) / R2, 256, 0, stream>>>(h2, W2, att_s2, att_d2, g, as2, ad2);
  k_agg2   <<<NN, 64, 0, stream>>>(srcp, offs, as2, ad2, g, b2, out);
}

// Round 4
// 413.928 us; speedup vs baseline: 2.1152x; 1.0336x over previous
//
#include <hip/hip_runtime.h>

#define NN 50000
#define EE 800000
#define ET 850000      // EE + NN self loops
#define FIN 256
#define HD 8
#define C1 16
#define HC 128         // HD*C1
#define NC 40
#define NEG 0.2f
#define SCAN_B 512
#define SCAN_NB 98     // ceil(NN/512)
#define R2 32          // rows per block in k_gemm2
#define BM 128         // k_gemm1 row tile
#define BK 16          // k_gemm1 k tile
#define GB1 ((NN + BM - 1) / BM)   // 391 blocks

__device__ __forceinline__ float leaky(float v){ return v > 0.f ? v : NEG * v; }

// K1: h1[N,128] = x[N,256] @ W1[256,128], register-blocked 128x128 tile, 8x8 micro.
// Fused: as1/ad1 attention dots + counts=1 init.
// 256 threads: rg = tid>>4 (row group, 8 rows), cg = tid&15 (col group, 8 cols).
__global__ __launch_bounds__(256, 4) void k_gemm1(const float* __restrict__ x,
                                                  const float* __restrict__ W1,
                                                  const float* __restrict__ att_s,
                                                  const float* __restrict__ att_d,
                                                  float* __restrict__ h1,
                                                  float* __restrict__ as1,
                                                  float* __restrict__ ad1,
                                                  int* __restrict__ counts){
  __shared__ float as[BK][BM + 4];   // +4 pad: staging writes 2-way (free), reads broadcast
  __shared__ float bs[BK][HC];
  const int tid = threadIdx.x;
  const int r0 = blockIdx.x * BM;
  const int rg = tid >> 4, cg = tid & 15;
  float acc[8][8];
#pragma unroll
  for (int i = 0; i < 8; i++)
#pragma unroll
    for (int j = 0; j < 8; j++) acc[i][j] = 0.f;

  for (int k0 = 0; k0 < FIN; k0 += BK){
    // stage A transposed: as[k][row]; 512 float4s, 2 per thread
#pragma unroll
    for (int q = 0; q < 2; q++){
      int f = tid + 256 * q;
      int row = f >> 2, kq = (f & 3) << 2;
      int gr = r0 + row; if (gr >= NN) gr = NN - 1;   // clamp (dup rows benign)
      const float4 v = *(const float4*)(x + (size_t)gr * FIN + k0 + kq);
      as[kq + 0][row] = v.x; as[kq + 1][row] = v.y;
      as[kq + 2][row] = v.z; as[kq + 3][row] = v.w;
    }
    // stage B direct: bs[k][c]; 512 float4s, 2 per thread
#pragma unroll
    for (int q = 0; q < 2; q++){
      int f = tid + 256 * q;
      int kk = f >> 5, cc = (f & 31) << 2;
      *(float4*)(&bs[kk][cc]) = *(const float4*)(W1 + (size_t)(k0 + kk) * HC + cc);
    }
    __syncthreads();
    for (int k = 0; k < BK; k++){
      float a[8], b[8];
      *(float4*)(a)     = *(const float4*)(&as[k][rg * 8]);
      *(float4*)(a + 4) = *(const float4*)(&as[k][rg * 8 + 4]);
      *(float4*)(b)     = *(const float4*)(&bs[k][cg * 8]);
      *(float4*)(b + 4) = *(const float4*)(&bs[k][cg * 8 + 4]);
#pragma unroll
      for (int i = 0; i < 8; i++)
#pragma unroll
        for (int j = 0; j < 8; j++) acc[i][j] += a[i] * b[j];
    }
    __syncthreads();
  }

  // epilogue: store h1, fused att dots (head = cg>>1), counts init
  const int c0 = cg * 8;
  float asv[8], adv[8];
  *(float4*)(asv)     = *(const float4*)(att_s + c0);
  *(float4*)(asv + 4) = *(const float4*)(att_s + c0 + 4);
  *(float4*)(adv)     = *(const float4*)(att_d + c0);
  *(float4*)(adv + 4) = *(const float4*)(att_d + c0 + 4);
#pragma unroll
  for (int i = 0; i < 8; i++){
    int gr = r0 + rg * 8 + i;
    bool ok = (gr < NN);
    float s = 0.f, d = 0.f;
#pragma unroll
    for (int j = 0; j < 8; j++){ s += acc[i][j] * asv[j]; d += acc[i][j] * adv[j]; }
    s += __shfl_xor(s, 1); d += __shfl_xor(d, 1);   // pair within head
    if (ok){
      *(float4*)(h1 + (size_t)gr * HC + c0)     = make_float4(acc[i][0], acc[i][1], acc[i][2], acc[i][3]);
      *(float4*)(h1 + (size_t)gr * HC + c0 + 4) = make_float4(acc[i][4], acc[i][5], acc[i][6], acc[i][7]);
      if ((cg & 1) == 0){
        as1[gr * 8 + (cg >> 1)] = s;
        ad1[gr * 8 + (cg >> 1)] = d;
      }
      if (cg == 0) counts[gr] = 1;   // self loop contributes 1 to in-degree
    }
  }
}

// K2: in-degree histogram (one atomic per edge)
__global__ void k_hist(const int* __restrict__ ei, int* __restrict__ counts){
  int e = blockIdx.x * blockDim.x + threadIdx.x;
  if (e >= EE) return;
  atomicAdd(&counts[ei[EE + e]], 1);
}

// K3a/b/c: exclusive scan of counts -> offs[0..NN], plus cursor copy
__global__ __launch_bounds__(SCAN_B) void k_scan1(const int* __restrict__ counts,
                                                  int* __restrict__ offs,
                                                  int* __restrict__ bsums){
  __shared__ int sm[SCAN_B];
  int b = blockIdx.x, t = threadIdx.x, i = b * SCAN_B + t;
  int v = (i < NN) ? counts[i] : 0;
  sm[t] = v; __syncthreads();
  for (int d = 1; d < SCAN_B; d <<= 1){
    int u = (t >= d) ? sm[t - d] : 0;
    __syncthreads();
    sm[t] += u;
    __syncthreads();
  }
  if (i < NN) offs[i + 1] = sm[t];
  if (t == SCAN_B - 1) bsums[b] = sm[t];
}

__global__ void k_scan2(int* __restrict__ bsums){
  if (blockIdx.x == 0 && threadIdx.x == 0){
    int run = 0;
    for (int b = 0; b < SCAN_NB; b++){ int v = bsums[b]; bsums[b] = run; run += v; }
  }
}

__global__ __launch_bounds__(SCAN_B) void k_scan3(int* __restrict__ offs,
                                                  const int* __restrict__ bsums,
                                                  int* __restrict__ cursor){
  int b = blockIdx.x, t = threadIdx.x, i = b * SCAN_B + t;
  if (i < NN){
    int v = offs[i + 1] + bsums[b];
    offs[i + 1] = v;
    if (i + 1 < NN) cursor[i + 1] = v;
  }
  if (b == 0 && t == 0){ offs[0] = 0; cursor[0] = 0; }
}

// K4: scatter SOURCE NODE IDS into CSR-by-dst order (self loops: src = dst = n)
__global__ void k_scatter(const int* __restrict__ ei, int* __restrict__ cursor,
                          int* __restrict__ srcp){
  int e = blockIdx.x * blockDim.x + threadIdx.x;
  if (e >= ET) return;
  int s, d;
  if (e < EE){ s = ei[e]; d = ei[EE + e]; } else { s = d = e - EE; }
  int pos = atomicAdd(&cursor[d], 1);
  srcp[pos] = s;
}

// K5: layer-1 single-pass online-softmax aggregate.
// One wave per node. lane = (half = lane>>5 edge parity, c4 = lane&31 float4 group, head = c4>>2).
__global__ __launch_bounds__(64) void k_agg1(const int* __restrict__ srcp,
                                             const int* __restrict__ offs,
                                             const float* __restrict__ as1,
                                             const float* __restrict__ ad1,
                                             const float* __restrict__ h1,
                                             const float* __restrict__ b1,
                                             float* __restrict__ h2){
  const int n = blockIdx.x, lane = threadIdx.x;
  const int half = lane >> 5, c4 = lane & 31, h = c4 >> 2;
  const int off = offs[n], deg = offs[n + 1] - off;
  const float adg = ad1[n * 8 + h];
  float m = -3.0e38f, den = 0.f;
  float ax = 0.f, ay = 0.f, az = 0.f, aw = 0.f;
  for (int i = half; i < deg; i += 2){
    int s = srcp[off + i];
    const float4 hr = *(const float4*)(h1 + (size_t)s * HC + c4 * 4);
    float v = leaky(as1[s * 8 + h] + adg);
    float mn = fmaxf(m, v);
    float r = __expf(m - mn);
    float w = __expf(v - mn);
    den = den * r + w;
    ax = ax * r + w * hr.x; ay = ay * r + w * hr.y;
    az = az * r + w * hr.z; aw = aw * r + w * hr.w;
    m = mn;
  }
  // combine the two edge-parity halves
  float mo = __shfl_xor(m, 32), dno = __shfl_xor(den, 32);
  float bx = __shfl_xor(ax, 32), by = __shfl_xor(ay, 32);
  float bz = __shfl_xor(az, 32), bw = __shfl_xor(aw, 32);
  float mn = fmaxf(m, mo);
  float ra = __expf(m - mn), rb = __expf(mo - mn);
  den = den * ra + dno * rb;
  ax = ax * ra + bx * rb; ay = ay * ra + by * rb;
  az = az * ra + bz * rb; aw = aw * ra + bw * rb;
  if (half == 0){
    float invd = 1.f / (den + 1e-16f);
    const float4 b4 = ((const float4*)b1)[c4];
    float4 o;
    o.x = ax * invd + b4.x; o.y = ay * invd + b4.y;
    o.z = az * invd + b4.z; o.w = aw * invd + b4.w;
    o.x = (o.x > 0.f) ? o.x : (__expf(o.x) - 1.f);
    o.y = (o.y > 0.f) ? o.y : (__expf(o.y) - 1.f);
    o.z = (o.z > 0.f) ? o.z : (__expf(o.z) - 1.f);
    o.w = (o.w > 0.f) ? o.w : (__expf(o.w) - 1.f);
    *(float4*)(h2 + (size_t)n * HC + c4 * 4) = o;
  }
}

// K6: g[N,40] = h2 @ W2 (32 rows/block, W2+h2 staged in LDS); fused att2 dots.
__global__ __launch_bounds__(256) void k_gemm2(const float* __restrict__ h2,
                                               const float* __restrict__ W2,
                                               const float* __restrict__ att_s2,
                                               const float* __restrict__ att_d2,
                                               float* __restrict__ g,
                                               float* __restrict__ as2,
                                               float* __restrict__ ad2){
  __shared__ float hs[R2][HC + 2];
  __shared__ float w2s[HC * NC];
  const int tid = threadIdx.x;
  const int r0 = blockIdx.x * R2;
  for (int i = tid; i < HC * NC; i += 256) w2s[i] = W2[i];
  for (int i = tid; i < R2 * HC; i += 256){
    int r = i >> 7, c = i & 127;
    hs[r][c] = (r0 + r < NN) ? h2[(size_t)(r0 + r) * HC + c] : 0.f;
  }
  __syncthreads();
  const int r = tid >> 3, j = tid & 7;
  float acc[5] = {0.f, 0.f, 0.f, 0.f, 0.f};
  for (int k = 0; k < HC; k++){
    float hv = hs[r][k];
#pragma unroll
    for (int q = 0; q < 5; q++) acc[q] += hv * w2s[k * NC + j + 8 * q];
  }
  const int node = r0 + r;
  if (node < NN){
    float s = 0.f, d = 0.f;
#pragma unroll
    for (int q = 0; q < 5; q++){
      int c = j + 8 * q;
      g[(size_t)node * NC + c] = acc[q];
      s += acc[q] * att_s2[c];
      d += acc[q] * att_d2[c];
    }
#pragma unroll
    for (int o = 1; o < 8; o <<= 1){ s += __shfl_xor(s, o); d += __shfl_xor(d, o); }
    if (j == 0){ as2[node] = s; ad2[node] = d; }
  }
}

// K7: layer-2 single-pass online-softmax aggregate + bias + log_softmax. One wave/node.
__global__ __launch_bounds__(64) void k_agg2(const int* __restrict__ srcp,
                                             const int* __restrict__ offs,
                                             const float* __restrict__ as2,
                                             const float* __restrict__ ad2,
                                             const float* __restrict__ g,
                                             const float* __restrict__ b2,
                                             float* __restrict__ out){
  const int n = blockIdx.x, lane = threadIdx.x;
  const int half = lane >> 5, c2 = lane & 31;
  const int off = offs[n], deg = offs[n + 1] - off;
  const float ad = ad2[n];
  const bool act = (c2 < 20);
  float m = -3.0e38f, den = 0.f, ax = 0.f, ay = 0.f;
  for (int i = half; i < deg; i += 2){
    int s = srcp[off + i];
    float v = leaky(as2[s] + ad);
    float gx = 0.f, gy = 0.f;
    if (act){
      const float2 gr = *(const float2*)(g + (size_t)s * NC + c2 * 2);
      gx = gr.x; gy = gr.y;
    }
    float mn = fmaxf(m, v);
    float r = __expf(m - mn), w = __expf(v - mn);
    den = den * r + w;
    ax = ax * r + w * gx; ay = ay * r + w * gy;
    m = mn;
  }
  float mo = __shfl_xor(m, 32), dno = __shfl_xor(den, 32);
  float bx = __shfl_xor(ax, 32), by = __shfl_xor(ay, 32);
  float mn = fmaxf(m, mo);
  float ra = __expf(m - mn), rb = __expf(mo - mn);
  den = den * ra + dno * rb;
  ax = ax * ra + bx * rb; ay = ay * ra + by * rb;
  __shared__ float fin[NC];
  if (half == 0 && act){
    float invd = 1.f / (den + 1e-16f);
    float f0 = ax * invd + b2[c2 * 2];
    float f1 = ay * invd + b2[c2 * 2 + 1];
    out[(size_t)n * NC + c2 * 2]     = f0;
    out[(size_t)n * NC + c2 * 2 + 1] = f1;
    fin[c2 * 2] = f0; fin[c2 * 2 + 1] = f1;
  }
  __syncthreads();
  float v = (lane < NC) ? fin[lane] : -3.4e38f;
  float mx = v;
#pragma unroll
  for (int o = 32; o; o >>= 1) mx = fmaxf(mx, __shfl_xor(mx, o));
  float ex = (lane < NC) ? __expf(v - mx) : 0.f;
#pragma unroll
  for (int o = 32; o; o >>= 1) ex += __shfl_xor(ex, o);
  float lse = mx + __logf(ex);
  if (lane < NC) out[(size_t)(NN * NC) + (size_t)n * NC + lane] = v - lse;
}

extern "C" void kernel_launch(void* const* d_in, const int* in_sizes, int n_in,
                              void* d_out, int out_size, void* d_ws, size_t ws_size,
                              hipStream_t stream){
  const float* x      = (const float*)d_in[0];
  const int*   ei     = (const int*)  d_in[1];   // [2,E] flat int32
  const float* W1     = (const float*)d_in[3];
  const float* att_s1 = (const float*)d_in[4];
  const float* att_d1 = (const float*)d_in[5];
  const float* b1     = (const float*)d_in[6];
  const float* W2     = (const float*)d_in[7];
  const float* att_s2 = (const float*)d_in[8];
  const float* att_d2 = (const float*)d_in[9];
  const float* b2     = (const float*)d_in[10];
  float* out = (float*)d_out;

  float* p   = (float*)d_ws;
  float* h1  = p; p += (size_t)NN * HC;
  float* h2  = p; p += (size_t)NN * HC;
  float* as1 = p; p += NN * HD;
  float* ad1 = p; p += NN * HD;
  float* g   = p; p += NN * NC;
  float* as2 = p; p += NN;
  float* ad2 = p; p += NN;
  int* counts = (int*)p;
  int* offs   = counts + NN;          // NN+1
  int* cursor = offs + NN + 4;        // padded
  int* srcp   = cursor + NN;          // ET source-node ids in CSR order
  int* bsums  = srcp + ET;            // SCAN_NB

  k_gemm1  <<<GB1, 256, 0, stream>>>(x, W1, att_s1, att_d1, h1, as1, ad1, counts);
  k_hist   <<<(EE + 255) / 256, 256, 0, stream>>>(ei, counts);
  k_scan1  <<<SCAN_NB, SCAN_B, 0, stream>>>(counts, offs, bsums);
  k_scan2  <<<1, 64, 0, stream>>>(bsums);
  k_scan3  <<<SCAN_NB, SCAN_B, 0, stream>>>(offs, bsums, cursor);
  k_scatter<<<(ET + 255) / 256, 256, 0, stream>>>(ei, cursor, srcp);
  k_agg1   <<<NN, 64, 0, stream>>>(srcp, offs, as1, ad1, h1, b1, h2);
  k_gemm2  <<<(NN + R2 - 1) / R2, 256, 0, stream>>>(h2, W2, att_s2, att_d2, g, as2, ad2);
  k_agg2   <<<NN, 64, 0, stream>>>(srcp, offs, as2, ad2, g, b2, out);
}

// Round 5
// 375.301 us; speedup vs baseline: 2.3329x; 1.1029x over previous
//
#include <hip/hip_runtime.h>

#define NN 50000
#define EE 800000
#define ET 850000      // EE + NN self loops
#define FIN 256
#define HD 8
#define C1 16
#define HC 128         // HD*C1
#define NC 40
#define NEG 0.2f
#define SCAN_B 512
#define SCAN_NB 98     // ceil(NN/512)
#define R2 32          // rows per block in k_gemm2
#define BM 128         // k_gemm1 row tile
#define BK 16          // k_gemm1 k tile
#define GB1 ((NN + BM - 1) / BM)   // 391 blocks

__device__ __forceinline__ float leaky(float v){ return v > 0.f ? v : NEG * v; }

// fp32 -> bf16 round-to-nearest-even (no NaNs in this workload)
__device__ __forceinline__ unsigned int f2bf(float f){
  unsigned int u = __float_as_uint(f);
  u += 0x7fffu + ((u >> 16) & 1u);
  return u >> 16;
}
__device__ __forceinline__ unsigned int pack2bf(float a, float b){
  return f2bf(a) | (f2bf(b) << 16);
}
__device__ __forceinline__ float bflo(unsigned int u){ return __uint_as_float(u << 16); }
__device__ __forceinline__ float bfhi(unsigned int u){ return __uint_as_float(u & 0xffff0000u); }

// K1: h1(bf16)[N,128] = x[N,256] @ W1[256,128], register-blocked 128x128, 8x8 micro.
// Fused: as1/ad1 attention dots + counts=1 init.
__global__ __launch_bounds__(256, 4) void k_gemm1(const float* __restrict__ x,
                                                  const float* __restrict__ W1,
                                                  const float* __restrict__ att_s,
                                                  const float* __restrict__ att_d,
                                                  unsigned short* __restrict__ h1b,
                                                  float* __restrict__ as1,
                                                  float* __restrict__ ad1,
                                                  int* __restrict__ counts){
  __shared__ float as[BK][BM + 4];
  __shared__ float bs[BK][HC];
  const int tid = threadIdx.x;
  const int r0 = blockIdx.x * BM;
  const int rg = tid >> 4, cg = tid & 15;
  float acc[8][8];
#pragma unroll
  for (int i = 0; i < 8; i++)
#pragma unroll
    for (int j = 0; j < 8; j++) acc[i][j] = 0.f;

  for (int k0 = 0; k0 < FIN; k0 += BK){
#pragma unroll
    for (int q = 0; q < 2; q++){
      int f = tid + 256 * q;
      int row = f >> 2, kq = (f & 3) << 2;
      int gr = r0 + row; if (gr >= NN) gr = NN - 1;
      const float4 v = *(const float4*)(x + (size_t)gr * FIN + k0 + kq);
      as[kq + 0][row] = v.x; as[kq + 1][row] = v.y;
      as[kq + 2][row] = v.z; as[kq + 3][row] = v.w;
    }
#pragma unroll
    for (int q = 0; q < 2; q++){
      int f = tid + 256 * q;
      int kk = f >> 5, cc = (f & 31) << 2;
      *(float4*)(&bs[kk][cc]) = *(const float4*)(W1 + (size_t)(k0 + kk) * HC + cc);
    }
    __syncthreads();
    for (int k = 0; k < BK; k++){
      float a[8], b[8];
      *(float4*)(a)     = *(const float4*)(&as[k][rg * 8]);
      *(float4*)(a + 4) = *(const float4*)(&as[k][rg * 8 + 4]);
      *(float4*)(b)     = *(const float4*)(&bs[k][cg * 8]);
      *(float4*)(b + 4) = *(const float4*)(&bs[k][cg * 8 + 4]);
#pragma unroll
      for (int i = 0; i < 8; i++)
#pragma unroll
        for (int j = 0; j < 8; j++) acc[i][j] += a[i] * b[j];
    }
    __syncthreads();
  }

  const int c0 = cg * 8;
  float asv[8], adv[8];
  *(float4*)(asv)     = *(const float4*)(att_s + c0);
  *(float4*)(asv + 4) = *(const float4*)(att_s + c0 + 4);
  *(float4*)(adv)     = *(const float4*)(att_d + c0);
  *(float4*)(adv + 4) = *(const float4*)(att_d + c0 + 4);
#pragma unroll
  for (int i = 0; i < 8; i++){
    int gr = r0 + rg * 8 + i;
    bool ok = (gr < NN);
    float s = 0.f, d = 0.f;
#pragma unroll
    for (int j = 0; j < 8; j++){ s += acc[i][j] * asv[j]; d += acc[i][j] * adv[j]; }
    s += __shfl_xor(s, 1); d += __shfl_xor(d, 1);
    if (ok){
      uint4 pk;
      pk.x = pack2bf(acc[i][0], acc[i][1]); pk.y = pack2bf(acc[i][2], acc[i][3]);
      pk.z = pack2bf(acc[i][4], acc[i][5]); pk.w = pack2bf(acc[i][6], acc[i][7]);
      *(uint4*)(h1b + (size_t)gr * HC + c0) = pk;
      if ((cg & 1) == 0){
        as1[gr * 8 + (cg >> 1)] = s;
        ad1[gr * 8 + (cg >> 1)] = d;
      }
      if (cg == 0) counts[gr] = 1;
    }
  }
}

// K2: in-degree histogram
__global__ void k_hist(const int* __restrict__ ei, int* __restrict__ counts){
  int e = blockIdx.x * blockDim.x + threadIdx.x;
  if (e >= EE) return;
  atomicAdd(&counts[ei[EE + e]], 1);
}

// K3a: per-block inclusive scan
__global__ __launch_bounds__(SCAN_B) void k_scan1(const int* __restrict__ counts,
                                                  int* __restrict__ offs,
                                                  int* __restrict__ bsums){
  __shared__ int sm[SCAN_B];
  int b = blockIdx.x, t = threadIdx.x, i = b * SCAN_B + t;
  int v = (i < NN) ? counts[i] : 0;
  sm[t] = v; __syncthreads();
  for (int d = 1; d < SCAN_B; d <<= 1){
    int u = (t >= d) ? sm[t - d] : 0;
    __syncthreads();
    sm[t] += u;
    __syncthreads();
  }
  if (i < NN) offs[i + 1] = sm[t];
  if (t == SCAN_B - 1) bsums[b] = sm[t];
}

// K3b: parallel exclusive scan of 98 block sums (one 128-thread block)
__global__ __launch_bounds__(128) void k_scan2(int* __restrict__ bsums){
  __shared__ int sm[128];
  int t = threadIdx.x;
  int v = (t < SCAN_NB) ? bsums[t] : 0;
  sm[t] = v; __syncthreads();
  for (int d = 1; d < 128; d <<= 1){
    int u = (t >= d) ? sm[t - d] : 0;
    __syncthreads();
    sm[t] += u;
    __syncthreads();
  }
  if (t < SCAN_NB) bsums[t] = sm[t] - v;   // exclusive
}

// K3c: add block offsets, produce offs + cursor
__global__ __launch_bounds__(SCAN_B) void k_scan3(int* __restrict__ offs,
                                                  const int* __restrict__ bsums,
                                                  int* __restrict__ cursor){
  int b = blockIdx.x, t = threadIdx.x, i = b * SCAN_B + t;
  if (i < NN){
    int v = offs[i + 1] + bsums[b];
    offs[i + 1] = v;
    if (i + 1 < NN) cursor[i + 1] = v;
  }
  if (b == 0 && t == 0){ offs[0] = 0; cursor[0] = 0; }
}

// K4: scatter source node ids into CSR-by-dst order
__global__ void k_scatter(const int* __restrict__ ei, int* __restrict__ cursor,
                          int* __restrict__ srcp){
  int e = blockIdx.x * blockDim.x + threadIdx.x;
  if (e >= ET) return;
  int s, d;
  if (e < EE){ s = ei[e]; d = ei[EE + e]; } else { s = d = e - EE; }
  int pos = atomicAdd(&cursor[d], 1);
  srcp[pos] = s;
}

// K5: layer-1 single-pass online-softmax aggregate, bf16 gather, 4 edges in flight.
// lane: q = lane>>4 (edge slot), t = lane&15 (8 channels each), head h = t>>1.
__global__ __launch_bounds__(64) void k_agg1(const int* __restrict__ srcp,
                                             const int* __restrict__ offs,
                                             const float* __restrict__ as1,
                                             const float* __restrict__ ad1,
                                             const unsigned short* __restrict__ h1b,
                                             const float* __restrict__ b1,
                                             float* __restrict__ h2){
  const int n = blockIdx.x, lane = threadIdx.x;
  const int q = lane >> 4, t = lane & 15, h = t >> 1;
  const int off = offs[n], deg = offs[n + 1] - off;
  const float adg = ad1[n * 8 + h];
  float m = -3.0e38f, den = 0.f;
  float acc[8];
#pragma unroll
  for (int c = 0; c < 8; c++) acc[c] = 0.f;

  int i = q;
  int s = (i < deg) ? srcp[off + i] : 0;
  while (i < deg){
    int inext = i + 4;
    int sn = (inext < deg) ? srcp[off + inext] : 0;    // prefetch
    const uint4 hv = *(const uint4*)(h1b + (size_t)s * HC + t * 8);
    float v = leaky(as1[s * 8 + h] + adg);
    float mn = fmaxf(m, v);
    float r = __expf(m - mn), w = __expf(v - mn);
    den = den * r + w;
    acc[0] = acc[0] * r + w * bflo(hv.x); acc[1] = acc[1] * r + w * bfhi(hv.x);
    acc[2] = acc[2] * r + w * bflo(hv.y); acc[3] = acc[3] * r + w * bfhi(hv.y);
    acc[4] = acc[4] * r + w * bflo(hv.z); acc[5] = acc[5] * r + w * bfhi(hv.z);
    acc[6] = acc[6] * r + w * bflo(hv.w); acc[7] = acc[7] * r + w * bfhi(hv.w);
    m = mn;
    s = sn; i = inext;
  }
  // combine 4 edge slots (xor 16, then 32)
#pragma unroll
  for (int o = 16; o <= 32; o <<= 1){
    float mo = __shfl_xor(m, o);
    float dno = __shfl_xor(den, o);
    float mn = fmaxf(m, mo);
    float ra = __expf(m - mn), rb = __expf(mo - mn);
    den = den * ra + dno * rb;
#pragma unroll
    for (int c = 0; c < 8; c++){
      float ao = __shfl_xor(acc[c], o);
      acc[c] = acc[c] * ra + ao * rb;
    }
    m = mn;
  }
  if (q == 0){
    float invd = 1.f / (den + 1e-16f);
    float o8[8];
    const float4 bA = *(const float4*)(b1 + t * 8);
    const float4 bB = *(const float4*)(b1 + t * 8 + 4);
    o8[0] = acc[0] * invd + bA.x; o8[1] = acc[1] * invd + bA.y;
    o8[2] = acc[2] * invd + bA.z; o8[3] = acc[3] * invd + bA.w;
    o8[4] = acc[4] * invd + bB.x; o8[5] = acc[5] * invd + bB.y;
    o8[6] = acc[6] * invd + bB.z; o8[7] = acc[7] * invd + bB.w;
#pragma unroll
    for (int c = 0; c < 8; c++) o8[c] = (o8[c] > 0.f) ? o8[c] : (__expf(o8[c]) - 1.f);
    *(float4*)(h2 + (size_t)n * HC + t * 8)     = make_float4(o8[0], o8[1], o8[2], o8[3]);
    *(float4*)(h2 + (size_t)n * HC + t * 8 + 4) = make_float4(o8[4], o8[5], o8[6], o8[7]);
  }
}

// K6: g(bf16)[N,40] = h2 @ W2; fused att2 dots.
__global__ __launch_bounds__(256) void k_gemm2(const float* __restrict__ h2,
                                               const float* __restrict__ W2,
                                               const float* __restrict__ att_s2,
                                               const float* __restrict__ att_d2,
                                               unsigned short* __restrict__ gb,
                                               float* __restrict__ as2,
                                               float* __restrict__ ad2){
  __shared__ float hs[R2][HC + 2];
  __shared__ float w2s[HC * NC];
  const int tid = threadIdx.x;
  const int r0 = blockIdx.x * R2;
  for (int i = tid; i < HC * NC; i += 256) w2s[i] = W2[i];
  for (int i = tid; i < R2 * HC; i += 256){
    int r = i >> 7, c = i & 127;
    hs[r][c] = (r0 + r < NN) ? h2[(size_t)(r0 + r) * HC + c] : 0.f;
  }
  __syncthreads();
  const int r = tid >> 3, j = tid & 7;
  float acc[5] = {0.f, 0.f, 0.f, 0.f, 0.f};
  for (int k = 0; k < HC; k++){
    float hv = hs[r][k];
#pragma unroll
    for (int q = 0; q < 5; q++) acc[q] += hv * w2s[k * NC + j + 8 * q];
  }
  const int node = r0 + r;
  if (node < NN){
    float s = 0.f, d = 0.f;
#pragma unroll
    for (int q = 0; q < 5; q++){
      int c = j + 8 * q;
      gb[(size_t)node * NC + c] = (unsigned short)f2bf(acc[q]);
      s += acc[q] * att_s2[c];
      d += acc[q] * att_d2[c];
    }
#pragma unroll
    for (int o = 1; o < 8; o <<= 1){ s += __shfl_xor(s, o); d += __shfl_xor(d, o); }
    if (j == 0){ as2[node] = s; ad2[node] = d; }
  }
}

// K7: layer-2 single-pass aggregate (bf16 gather) + bias + log_softmax. One wave/node.
__global__ __launch_bounds__(64) void k_agg2(const int* __restrict__ srcp,
                                             const int* __restrict__ offs,
                                             const float* __restrict__ as2,
                                             const float* __restrict__ ad2,
                                             const unsigned short* __restrict__ gb,
                                             const float* __restrict__ b2,
                                             float* __restrict__ out){
  const int n = blockIdx.x, lane = threadIdx.x;
  const int half = lane >> 5, c2 = lane & 31;
  const int off = offs[n], deg = offs[n + 1] - off;
  const float ad = ad2[n];
  const bool act = (c2 < 20);
  float m = -3.0e38f, den = 0.f, ax = 0.f, ay = 0.f;
  int i = half;
  int s = (i < deg) ? srcp[off + i] : 0;
  while (i < deg){
    int inext = i + 2;
    int sn = (inext < deg) ? srcp[off + inext] : 0;
    float v = leaky(as2[s] + ad);
    float gx = 0.f, gy = 0.f;
    if (act){
      unsigned int u = *(const unsigned int*)(gb + (size_t)s * NC + c2 * 2);
      gx = bflo(u); gy = bfhi(u);
    }
    float mn = fmaxf(m, v);
    float r = __expf(m - mn), w = __expf(v - mn);
    den = den * r + w;
    ax = ax * r + w * gx; ay = ay * r + w * gy;
    m = mn;
    s = sn; i = inext;
  }
  float mo = __shfl_xor(m, 32), dno = __shfl_xor(den, 32);
  float bx = __shfl_xor(ax, 32), by = __shfl_xor(ay, 32);
  float mn = fmaxf(m, mo);
  float ra = __expf(m - mn), rb = __expf(mo - mn);
  den = den * ra + dno * rb;
  ax = ax * ra + bx * rb; ay = ay * ra + by * rb;
  __shared__ float fin[NC];
  if (half == 0 && act){
    float invd = 1.f / (den + 1e-16f);
    float f0 = ax * invd + b2[c2 * 2];
    float f1 = ay * invd + b2[c2 * 2 + 1];
    out[(size_t)n * NC + c2 * 2]     = f0;
    out[(size_t)n * NC + c2 * 2 + 1] = f1;
    fin[c2 * 2] = f0; fin[c2 * 2 + 1] = f1;
  }
  __syncthreads();
  float v = (lane < NC) ? fin[lane] : -3.4e38f;
  float mx = v;
#pragma unroll
  for (int o = 32; o; o >>= 1) mx = fmaxf(mx, __shfl_xor(mx, o));
  float ex = (lane < NC) ? __expf(v - mx) : 0.f;
#pragma unroll
  for (int o = 32; o; o >>= 1) ex += __shfl_xor(ex, o);
  float lse = mx + __logf(ex);
  if (lane < NC) out[(size_t)(NN * NC) + (size_t)n * NC + lane] = v - lse;
}

extern "C" void kernel_launch(void* const* d_in, const int* in_sizes, int n_in,
                              void* d_out, int out_size, void* d_ws, size_t ws_size,
                              hipStream_t stream){
  const float* x      = (const float*)d_in[0];
  const int*   ei     = (const int*)  d_in[1];
  const float* W1     = (const float*)d_in[3];
  const float* att_s1 = (const float*)d_in[4];
  const float* att_d1 = (const float*)d_in[5];
  const float* b1     = (const float*)d_in[6];
  const float* W2     = (const float*)d_in[7];
  const float* att_s2 = (const float*)d_in[8];
  const float* att_d2 = (const float*)d_in[9];
  const float* b2     = (const float*)d_in[10];
  float* out = (float*)d_out;

  char* wp = (char*)d_ws;
  float* h2  = (float*)wp;           wp += (size_t)NN * HC * 4;
  float* as1 = (float*)wp;           wp += (size_t)NN * HD * 4;
  float* ad1 = (float*)wp;           wp += (size_t)NN * HD * 4;
  float* as2 = (float*)wp;           wp += (size_t)NN * 4;
  float* ad2 = (float*)wp;           wp += (size_t)NN * 4;
  unsigned short* h1b = (unsigned short*)wp; wp += (size_t)NN * HC * 2;
  unsigned short* gb  = (unsigned short*)wp; wp += (size_t)NN * NC * 2;
  int* counts = (int*)wp;            wp += (size_t)NN * 4;
  int* offs   = (int*)wp;            wp += (size_t)(NN + 4) * 4;
  int* cursor = (int*)wp;            wp += (size_t)NN * 4;
  int* srcp   = (int*)wp;            wp += (size_t)ET * 4;
  int* bsums  = (int*)wp;

  k_gemm1  <<<GB1, 256, 0, stream>>>(x, W1, att_s1, att_d1, h1b, as1, ad1, counts);
  k_hist   <<<(EE + 255) / 256, 256, 0, stream>>>(ei, counts);
  k_scan1  <<<SCAN_NB, SCAN_B, 0, stream>>>(counts, offs, bsums);
  k_scan2  <<<1, 128, 0, stream>>>(bsums);
  k_scan3  <<<SCAN_NB, SCAN_B, 0, stream>>>(offs, bsums, cursor);
  k_scatter<<<(ET + 255) / 256, 256, 0, stream>>>(ei, cursor, srcp);
  k_agg1   <<<NN, 64, 0, stream>>>(srcp, offs, as1, ad1, h1b, b1, h2);
  k_gemm2  <<<(NN + R2 - 1) / R2, 256, 0, stream>>>(h2, W2, att_s2, att_d2, gb, as2, ad2);
  k_agg2   <<<NN, 64, 0, stream>>>(srcp, offs, as2, ad2, gb, b2, out);
}

// Round 6
// 347.178 us; speedup vs baseline: 2.5219x; 1.0810x over previous
//
#include <hip/hip_runtime.h>

#define NN 50000
#define EE 800000
#define ET 850000      // EE + NN self loops
#define FIN 256
#define HD 8
#define C1 16
#define HC 128         // HD*C1
#define NC 40
#define NEG 0.2f
#define SCAN_B 512
#define SCAN_NB 98     // ceil(NN/512)
#define R2 32          // rows per block in k_gemm2
#define BM 64          // k_gemm1 row tile
#define BK 32          // k_gemm1 k tile
#define GB1 ((NN + BM - 1) / BM)   // 782 blocks (~3/CU resident)

__device__ __forceinline__ float leaky(float v){ return v > 0.f ? v : NEG * v; }

// fp32 -> bf16 round-to-nearest-even (no NaNs in this workload)
__device__ __forceinline__ unsigned int f2bf(float f){
  unsigned int u = __float_as_uint(f);
  u += 0x7fffu + ((u >> 16) & 1u);
  return u >> 16;
}
__device__ __forceinline__ unsigned int pack2bf(float a, float b){
  return f2bf(a) | (f2bf(b) << 16);
}
__device__ __forceinline__ float bflo(unsigned int u){ return __uint_as_float(u << 16); }
__device__ __forceinline__ float bfhi(unsigned int u){ return __uint_as_float(u & 0xffff0000u); }

// K1: h1(bf16)[N,128] = x[N,256] @ W1[256,128]. 64x128 block tile, 4x8 micro.
// Column split {cg*4, 64+cg*4} keeps LDS fragment reads at <=2-way aliasing (free).
// Fused: as1/ad1 attention dots + grid-stride in-degree histogram (counts pre-zeroed).
__global__ __launch_bounds__(256, 4) void k_gemm1(const float* __restrict__ x,
                                                  const float* __restrict__ W1,
                                                  const float* __restrict__ att_s,
                                                  const float* __restrict__ att_d,
                                                  const int* __restrict__ ei,
                                                  unsigned short* __restrict__ h1b,
                                                  float* __restrict__ as1,
                                                  float* __restrict__ ad1,
                                                  int* __restrict__ counts){
  __shared__ float as[BK][BM + 1];   // stride 65 == 1 mod 32 -> staging writes <=2-way
  __shared__ float bs[BK][HC];
  const int tid = threadIdx.x;
  const int r0 = blockIdx.x * BM;
  const int rg = tid >> 4, cg = tid & 15;
  float acc[4][8];
#pragma unroll
  for (int i = 0; i < 4; i++)
#pragma unroll
    for (int j = 0; j < 8; j++) acc[i][j] = 0.f;

  for (int k0 = 0; k0 < FIN; k0 += BK){
    // stage A transposed: 64 rows x 32 k = 512 float4, 2 per thread
#pragma unroll
    for (int q = 0; q < 2; q++){
      int f = tid + 256 * q;
      int row = f >> 3, kq = (f & 7) << 2;
      int gr = r0 + row; if (gr >= NN) gr = NN - 1;   // clamp (dup rows benign)
      const float4 v = *(const float4*)(x + (size_t)gr * FIN + k0 + kq);
      as[kq + 0][row] = v.x; as[kq + 1][row] = v.y;
      as[kq + 2][row] = v.z; as[kq + 3][row] = v.w;
    }
    // stage B direct: 32 x 128 = 1024 float4, 4 per thread
#pragma unroll
    for (int q = 0; q < 4; q++){
      int f = tid + 256 * q;
      int kk = f >> 5, cc = (f & 31) << 2;
      *(float4*)(&bs[kk][cc]) = *(const float4*)(W1 + (size_t)(k0 + kk) * HC + cc);
    }
    __syncthreads();
#pragma unroll
    for (int k = 0; k < BK; k++){
      float a[4], b[8];
      *(float4*)(a)     = *(const float4*)(&as[k][rg * 4]);
      *(float4*)(b)     = *(const float4*)(&bs[k][cg * 4]);
      *(float4*)(b + 4) = *(const float4*)(&bs[k][64 + cg * 4]);
#pragma unroll
      for (int i = 0; i < 4; i++)
#pragma unroll
        for (int j = 0; j < 8; j++) acc[i][j] += a[i] * b[j];
    }
    __syncthreads();
  }

  // epilogue: cols cA..cA+3 (head cg>>2) and cB..cB+3 (head 4+(cg>>2))
  const int cA = cg * 4, cB = 64 + cg * 4;
  float s_att[8], d_att[8];
  *(float4*)(s_att)     = *(const float4*)(att_s + cA);
  *(float4*)(s_att + 4) = *(const float4*)(att_s + cB);
  *(float4*)(d_att)     = *(const float4*)(att_d + cA);
  *(float4*)(d_att + 4) = *(const float4*)(att_d + cB);
#pragma unroll
  for (int i = 0; i < 4; i++){
    int gr = r0 + rg * 4 + i;
    float sA = 0.f, dA = 0.f, sB = 0.f, dB = 0.f;
#pragma unroll
    for (int j = 0; j < 4; j++){
      sA += acc[i][j] * s_att[j];     dA += acc[i][j] * d_att[j];
      sB += acc[i][j + 4] * s_att[j + 4]; dB += acc[i][j + 4] * d_att[j + 4];
    }
    // reduce over the 4 lanes (cg%4) covering the 16 channels of each head
    sA += __shfl_xor(sA, 1); sA += __shfl_xor(sA, 2);
    dA += __shfl_xor(dA, 1); dA += __shfl_xor(dA, 2);
    sB += __shfl_xor(sB, 1); sB += __shfl_xor(sB, 2);
    dB += __shfl_xor(dB, 1); dB += __shfl_xor(dB, 2);
    if (gr < NN){
      uint2 pA, pB;
      pA.x = pack2bf(acc[i][0], acc[i][1]); pA.y = pack2bf(acc[i][2], acc[i][3]);
      pB.x = pack2bf(acc[i][4], acc[i][5]); pB.y = pack2bf(acc[i][6], acc[i][7]);
      *(uint2*)(h1b + (size_t)gr * HC + cA) = pA;
      *(uint2*)(h1b + (size_t)gr * HC + cB) = pB;
      if ((cg & 3) == 0){
        int hA = cg >> 2, hB = 4 + (cg >> 2);
        as1[gr * 8 + hA] = sA; ad1[gr * 8 + hA] = dA;
        as1[gr * 8 + hB] = sB; ad1[gr * 8 + hB] = dB;
      }
    }
  }
  // fused in-degree histogram (counts zeroed via memset; self-loop +1 added in scan)
  for (int e = blockIdx.x * 256 + tid; e < EE; e += GB1 * 256)
    atomicAdd(&counts[ei[EE + e]], 1);
}

// K3a: per-block inclusive scan (+1 per node = self loop)
__global__ __launch_bounds__(SCAN_B) void k_scan1(const int* __restrict__ counts,
                                                  int* __restrict__ offs,
                                                  int* __restrict__ bsums){
  __shared__ int sm[SCAN_B];
  int b = blockIdx.x, t = threadIdx.x, i = b * SCAN_B + t;
  int v = (i < NN) ? counts[i] + 1 : 0;
  sm[t] = v; __syncthreads();
  for (int d = 1; d < SCAN_B; d <<= 1){
    int u = (t >= d) ? sm[t - d] : 0;
    __syncthreads();
    sm[t] += u;
    __syncthreads();
  }
  if (i < NN) offs[i + 1] = sm[t];
  if (t == SCAN_B - 1) bsums[b] = sm[t];
}

// K3b: parallel exclusive scan of 98 block sums
__global__ __launch_bounds__(128) void k_scan2(int* __restrict__ bsums){
  __shared__ int sm[128];
  int t = threadIdx.x;
  int v = (t < SCAN_NB) ? bsums[t] : 0;
  sm[t] = v; __syncthreads();
  for (int d = 1; d < 128; d <<= 1){
    int u = (t >= d) ? sm[t - d] : 0;
    __syncthreads();
    sm[t] += u;
    __syncthreads();
  }
  if (t < SCAN_NB) bsums[t] = sm[t] - v;   // exclusive
}

// K3c: add block offsets, produce offs + cursor
__global__ __launch_bounds__(SCAN_B) void k_scan3(int* __restrict__ offs,
                                                  const int* __restrict__ bsums,
                                                  int* __restrict__ cursor){
  int b = blockIdx.x, t = threadIdx.x, i = b * SCAN_B + t;
  if (i < NN){
    int v = offs[i + 1] + bsums[b];
    offs[i + 1] = v;
    if (i + 1 < NN) cursor[i + 1] = v;
  }
  if (b == 0 && t == 0){ offs[0] = 0; cursor[0] = 0; }
}

// K4: scatter source node ids into CSR-by-dst order
__global__ void k_scatter(const int* __restrict__ ei, int* __restrict__ cursor,
                          int* __restrict__ srcp){
  int e = blockIdx.x * blockDim.x + threadIdx.x;
  if (e >= ET) return;
  int s, d;
  if (e < EE){ s = ei[e]; d = ei[EE + e]; } else { s = d = e - EE; }
  int pos = atomicAdd(&cursor[d], 1);
  srcp[pos] = s;
}

// K5: layer-1 single-pass online-softmax aggregate, bf16 gather, 4 edges in flight.
__global__ __launch_bounds__(64) void k_agg1(const int* __restrict__ srcp,
                                             const int* __restrict__ offs,
                                             const float* __restrict__ as1,
                                             const float* __restrict__ ad1,
                                             const unsigned short* __restrict__ h1b,
                                             const float* __restrict__ b1,
                                             float* __restrict__ h2){
  const int n = blockIdx.x, lane = threadIdx.x;
  const int q = lane >> 4, t = lane & 15, h = t >> 1;
  const int off = offs[n], deg = offs[n + 1] - off;
  const float adg = ad1[n * 8 + h];
  float m = -3.0e38f, den = 0.f;
  float acc[8];
#pragma unroll
  for (int c = 0; c < 8; c++) acc[c] = 0.f;

  int i = q;
  int s = (i < deg) ? srcp[off + i] : 0;
  while (i < deg){
    int inext = i + 4;
    int sn = (inext < deg) ? srcp[off + inext] : 0;
    const uint4 hv = *(const uint4*)(h1b + (size_t)s * HC + t * 8);
    float v = leaky(as1[s * 8 + h] + adg);
    float mn = fmaxf(m, v);
    float r = __expf(m - mn), w = __expf(v - mn);
    den = den * r + w;
    acc[0] = acc[0] * r + w * bflo(hv.x); acc[1] = acc[1] * r + w * bfhi(hv.x);
    acc[2] = acc[2] * r + w * bflo(hv.y); acc[3] = acc[3] * r + w * bfhi(hv.y);
    acc[4] = acc[4] * r + w * bflo(hv.z); acc[5] = acc[5] * r + w * bfhi(hv.z);
    acc[6] = acc[6] * r + w * bflo(hv.w); acc[7] = acc[7] * r + w * bfhi(hv.w);
    m = mn;
    s = sn; i = inext;
  }
#pragma unroll
  for (int o = 16; o <= 32; o <<= 1){
    float mo = __shfl_xor(m, o);
    float dno = __shfl_xor(den, o);
    float mn = fmaxf(m, mo);
    float ra = __expf(m - mn), rb = __expf(mo - mn);
    den = den * ra + dno * rb;
#pragma unroll
    for (int c = 0; c < 8; c++){
      float ao = __shfl_xor(acc[c], o);
      acc[c] = acc[c] * ra + ao * rb;
    }
    m = mn;
  }
  if (q == 0){
    float invd = 1.f / (den + 1e-16f);
    float o8[8];
    const float4 bA = *(const float4*)(b1 + t * 8);
    const float4 bB = *(const float4*)(b1 + t * 8 + 4);
    o8[0] = acc[0] * invd + bA.x; o8[1] = acc[1] * invd + bA.y;
    o8[2] = acc[2] * invd + bA.z; o8[3] = acc[3] * invd + bA.w;
    o8[4] = acc[4] * invd + bB.x; o8[5] = acc[5] * invd + bB.y;
    o8[6] = acc[6] * invd + bB.z; o8[7] = acc[7] * invd + bB.w;
#pragma unroll
    for (int c = 0; c < 8; c++) o8[c] = (o8[c] > 0.f) ? o8[c] : (__expf(o8[c]) - 1.f);
    *(float4*)(h2 + (size_t)n * HC + t * 8)     = make_float4(o8[0], o8[1], o8[2], o8[3]);
    *(float4*)(h2 + (size_t)n * HC + t * 8 + 4) = make_float4(o8[4], o8[5], o8[6], o8[7]);
  }
}

// K6: g(bf16)[N,40] = h2 @ W2; fused att2 dots.
__global__ __launch_bounds__(256) void k_gemm2(const float* __restrict__ h2,
                                               const float* __restrict__ W2,
                                               const float* __restrict__ att_s2,
                                               const float* __restrict__ att_d2,
                                               unsigned short* __restrict__ gb,
                                               float* __restrict__ as2,
                                               float* __restrict__ ad2){
  __shared__ float hs[R2][HC + 2];
  __shared__ float w2s[HC * NC];
  const int tid = threadIdx.x;
  const int r0 = blockIdx.x * R2;
  for (int i = tid; i < HC * NC; i += 256) w2s[i] = W2[i];
  for (int i = tid; i < R2 * HC; i += 256){
    int r = i >> 7, c = i & 127;
    hs[r][c] = (r0 + r < NN) ? h2[(size_t)(r0 + r) * HC + c] : 0.f;
  }
  __syncthreads();
  const int r = tid >> 3, j = tid & 7;
  float acc[5] = {0.f, 0.f, 0.f, 0.f, 0.f};
  for (int k = 0; k < HC; k++){
    float hv = hs[r][k];
#pragma unroll
    for (int q = 0; q < 5; q++) acc[q] += hv * w2s[k * NC + j + 8 * q];
  }
  const int node = r0 + r;
  if (node < NN){
    float s = 0.f, d = 0.f;
#pragma unroll
    for (int q = 0; q < 5; q++){
      int c = j + 8 * q;
      gb[(size_t)node * NC + c] = (unsigned short)f2bf(acc[q]);
      s += acc[q] * att_s2[c];
      d += acc[q] * att_d2[c];
    }
#pragma unroll
    for (int o = 1; o < 8; o <<= 1){ s += __shfl_xor(s, o); d += __shfl_xor(d, o); }
    if (j == 0){ as2[node] = s; ad2[node] = d; }
  }
}

// K7: layer-2 single-pass aggregate (bf16 gather) + bias + log_softmax. One wave/node.
__global__ __launch_bounds__(64) void k_agg2(const int* __restrict__ srcp,
                                             const int* __restrict__ offs,
                                             const float* __restrict__ as2,
                                             const float* __restrict__ ad2,
                                             const unsigned short* __restrict__ gb,
                                             const float* __restrict__ b2,
                                             float* __restrict__ out){
  const int n = blockIdx.x, lane = threadIdx.x;
  const int half = lane >> 5, c2 = lane & 31;
  const int off = offs[n], deg = offs[n + 1] - off;
  const float ad = ad2[n];
  const bool act = (c2 < 20);
  float m = -3.0e38f, den = 0.f, ax = 0.f, ay = 0.f;
  int i = half;
  int s = (i < deg) ? srcp[off + i] : 0;
  while (i < deg){
    int inext = i + 2;
    int sn = (inext < deg) ? srcp[off + inext] : 0;
    float v = leaky(as2[s] + ad);
    float gx = 0.f, gy = 0.f;
    if (act){
      unsigned int u = *(const unsigned int*)(gb + (size_t)s * NC + c2 * 2);
      gx = bflo(u); gy = bfhi(u);
    }
    float mn = fmaxf(m, v);
    float r = __expf(m - mn), w = __expf(v - mn);
    den = den * r + w;
    ax = ax * r + w * gx; ay = ay * r + w * gy;
    m = mn;
    s = sn; i = inext;
  }
  float mo = __shfl_xor(m, 32), dno = __shfl_xor(den, 32);
  float bx = __shfl_xor(ax, 32), by = __shfl_xor(ay, 32);
  float mn = fmaxf(m, mo);
  float ra = __expf(m - mn), rb = __expf(mo - mn);
  den = den * ra + dno * rb;
  ax = ax * ra + bx * rb; ay = ay * ra + by * rb;
  __shared__ float fin[NC];
  if (half == 0 && act){
    float invd = 1.f / (den + 1e-16f);
    float f0 = ax * invd + b2[c2 * 2];
    float f1 = ay * invd + b2[c2 * 2 + 1];
    out[(size_t)n * NC + c2 * 2]     = f0;
    out[(size_t)n * NC + c2 * 2 + 1] = f1;
    fin[c2 * 2] = f0; fin[c2 * 2 + 1] = f1;
  }
  __syncthreads();
  float v = (lane < NC) ? fin[lane] : -3.4e38f;
  float mx = v;
#pragma unroll
  for (int o = 32; o; o >>= 1) mx = fmaxf(mx, __shfl_xor(mx, o));
  float ex = (lane < NC) ? __expf(v - mx) : 0.f;
#pragma unroll
  for (int o = 32; o; o >>= 1) ex += __shfl_xor(ex, o);
  float lse = mx + __logf(ex);
  if (lane < NC) out[(size_t)(NN * NC) + (size_t)n * NC + lane] = v - lse;
}

extern "C" void kernel_launch(void* const* d_in, const int* in_sizes, int n_in,
                              void* d_out, int out_size, void* d_ws, size_t ws_size,
                              hipStream_t stream){
  const float* x      = (const float*)d_in[0];
  const int*   ei     = (const int*)  d_in[1];
  const float* W1     = (const float*)d_in[3];
  const float* att_s1 = (const float*)d_in[4];
  const float* att_d1 = (const float*)d_in[5];
  const float* b1     = (const float*)d_in[6];
  const float* W2     = (const float*)d_in[7];
  const float* att_s2 = (const float*)d_in[8];
  const float* att_d2 = (const float*)d_in[9];
  const float* b2     = (const float*)d_in[10];
  float* out = (float*)d_out;

  char* wp = (char*)d_ws;
  float* h2  = (float*)wp;           wp += (size_t)NN * HC * 4;
  float* as1 = (float*)wp;           wp += (size_t)NN * HD * 4;
  float* ad1 = (float*)wp;           wp += (size_t)NN * HD * 4;
  float* as2 = (float*)wp;           wp += (size_t)NN * 4;
  float* ad2 = (float*)wp;           wp += (size_t)NN * 4;
  unsigned short* h1b = (unsigned short*)wp; wp += (size_t)NN * HC * 2;
  unsigned short* gb  = (unsigned short*)wp; wp += (size_t)NN * NC * 2;
  int* counts = (int*)wp;            wp += (size_t)NN * 4;
  int* offs   = (int*)wp;            wp += (size_t)(NN + 4) * 4;
  int* cursor = (int*)wp;            wp += (size_t)NN * 4;
  int* srcp   = (int*)wp;            wp += (size_t)ET * 4;
  int* bsums  = (int*)wp;

  hipMemsetAsync(counts, 0, (size_t)NN * sizeof(int), stream);
  k_gemm1  <<<GB1, 256, 0, stream>>>(x, W1, att_s1, att_d1, ei, h1b, as1, ad1, counts);
  k_scan1  <<<SCAN_NB, SCAN_B, 0, stream>>>(counts, offs, bsums);
  k_scan2  <<<1, 128, 0, stream>>>(bsums);
  k_scan3  <<<SCAN_NB, SCAN_B, 0, stream>>>(offs, bsums, cursor);
  k_scatter<<<(ET + 255) / 256, 256, 0, stream>>>(ei, cursor, srcp);
  k_agg1   <<<NN, 64, 0, stream>>>(srcp, offs, as1, ad1, h1b, b1, h2);
  k_gemm2  <<<(NN + R2 - 1) / R2, 256, 0, stream>>>(h2, W2, att_s2, att_d2, gb, as2, ad2);
  k_agg2   <<<NN, 64, 0, stream>>>(srcp, offs, as2, ad2, gb, b2, out);
}